// Round 10
// baseline (213.090 us; speedup 1.0000x reference)
//
#include <hip/hip_runtime.h>

// Fused LSTM(H=128) + 3-layer MLP head, fp16 MFMA (16x16x32), fp32 state.
// B=8192 rows, T=30 steps. 256 blocks x 512 threads (8 waves), 32 rows/block.
// ROUND 9 (resubmit; round-9 bench was a container-infra failure, no signal).
// Single-barrier warm steps. r8 showed ~27% of cycles with neither
// pipe issuing: the 2-phase warm (MFMA phase | barrier | VALU phase | barrier)
// serializes the pipes. Every intra-step dep except h/o1 is IN-LANE (gates
// consume acc in regs), so with dbuf hp/o1p + 3-buf xp a warm step is ONE
// region: stage x(i+1) | z(i)+MLP1(i-1) MFMA | gates(i) VALU | MLP2(i-2) MFMA
// | head-reduce | out(i-3). 24 barriers for warm (was 46); MFMA+VALU+trans
// co-resident per region. Head = in-register reduce: relu(m2)*Wout,
// __shfl_xor over the 16 c16 lanes, atomicAdd (ds_add_f32) into dbuf pS[2][32]
// -> o2s table + head phase deleted. Tail keeps the p-feedback chain at 3
// barriers/step: TA z(s)+MLP1(s-1) | TB MLP2(s-1)+reduce->pSt | TC p-inject+
// gates(s)+out(s-1). Buffer parities verified per-step in comments below.
// Prior lessons kept: 2 waves/SIMD is the reg ceiling (r4/r5 spills, watch
// FETCH); fp16 single precision (r7, absmax 0.001953125); p-inject via VALU
// acc += p*wi7 (r7); gather staging stays same-region (r8: split was neutral).
// - Wave w owns output cols [16w,16w+16); 2 M-tiles (rows 0-15,16-31).
// - 16x16x32 layouts: A/B: row|col=lane&15, k=(lane>>4)*8+j; C/D: col=lane&15,
//   row=(lane>>4)*4+reg (m89-verified).
// - A-panels [16 rows][40 halfs] (32 data + 8 pad): 16B-aligned b128 reads.
// - fp32: accumulators, c-state, gates, head reduce, feedback p.

#define T_STEPS 30
#define WARM_N  24

typedef _Float16 h8 __attribute__((ext_vector_type(8)));     // 8 fp16 = 4 VGPRs
typedef __attribute__((ext_vector_type(4))) float float4v;   // MFMA 16x16 C/D

struct FeatPtrs { const float* f[7]; };

#if __has_builtin(__builtin_amdgcn_rcpf)
#define RCP(x) __builtin_amdgcn_rcpf(x)
#else
#define RCP(x) (1.0f/(x))
#endif

__device__ __forceinline__ float sigm(float x){ return RCP(1.0f + __expf(-x)); }
__device__ __forceinline__ float tanh_(float x){ return 1.0f - 2.0f*RCP(1.0f + __expf(2.0f*x)); }

// ---------------- weight pack kernel ----------------
// 224 frags of 512 fp16 (1 KB each), frag elem (lane,j):
//   col16 = lane&15, kk = (lane>>4)*8 + j  (K=32 per fragment)
// frags 0..159 : z-weights [wt 0..7][g 0..3][ks 0..4]
//   ks=0: x-frag: kk<8 -> Wi[kk][col], kk>=8 -> 0
//   ks 1..4: Wh[(ks-1)*32+kk][col];  col = g*128+wt*16+col16
// frags 160..191: W1 [wt][ks 0..3]: W1[ks*32+kk][wt*16+col16]
// frags 192..223: W2 same layout.
__global__ void pack_weights(const float* __restrict__ Wi, const float* __restrict__ Wh,
                             const float* __restrict__ W1, const float* __restrict__ W2,
                             _Float16* __restrict__ ws)
{
  int idx = blockIdx.x * 256 + threadIdx.x;
  if (idx >= 224 * 512) return;
  int f    = idx >> 9;
  int r    = idx & 511;
  int lane = r >> 3, j = r & 7;
  int kk   = ((lane >> 4) << 3) + j;     // 0..31
  int c16  = lane & 15;
  float v = 0.0f;
  if (f < 160){
    int wt = f / 20, rem = f % 20, g = rem / 5, ks = rem % 5;
    int col = g * 128 + wt * 16 + c16;
    if (ks == 0) v = (kk < 8) ? Wi[kk * 512 + col] : 0.0f;
    else         v = Wh[((ks - 1) * 32 + kk) * 512 + col];
  } else {
    int f2 = f - 160;                    // 0..63
    const float* W = (f2 < 32) ? W1 : W2;
    int f3 = f2 & 31;
    int wt = f3 >> 2, ks = f3 & 3;
    v = W[(ks * 32 + kk) * 128 + wt * 16 + c16];
  }
  ws[idx] = (_Float16)v;
}

#define MFMA16 __builtin_amdgcn_mfma_f32_16x16x32_f16

// ---------------- main kernel ----------------
__global__ __launch_bounds__(512, 2)
void lstm_mfma(FeatPtrs fp, const float* __restrict__ irr,
               const _Float16* __restrict__ wsb,
               const float* __restrict__ bz, const float* __restrict__ b1,
               const float* __restrict__ b2, const float* __restrict__ Wout,
               const float* __restrict__ bout, float* __restrict__ out)
{
  // A-panels per buffer: [kstep 0..3][m-tile 0..1][16 rows][40 halfs]
  __shared__ __align__(16) _Float16 xp[3][1280];    // x, triple-buffered steps
  __shared__ __align__(16) _Float16 hp[2][5120];    // h, double-buffered
  __shared__ __align__(16) _Float16 o1p[2][5120];   // o1, double-buffered
  __shared__ float pS[2][32];                       // warm head accum (dbuf)
  __shared__ float pSt[32];                         // tail p accum

  const int t   = threadIdx.x;
  const int l   = t & 63;
  const int w   = t >> 6;        // wave 0..7, owns cols [16w,16w+16)
  const int c16 = l & 15;
  const int kq  = l >> 4;        // 0..3
  const int r0  = blockIdx.x * 32;

  // weight fragments -> registers (112 VGPRs)
  h8 Bz[4][5], B1f[4], B2f[4];
  {
    const h8* f8 = (const h8*)wsb;
#pragma unroll
    for (int g = 0; g < 4; ++g)
#pragma unroll
      for (int ks = 0; ks < 5; ++ks)
        Bz[g][ks] = f8[((w * 4 + g) * 5 + ks) * 64 + l];
#pragma unroll
    for (int ks = 0; ks < 4; ++ks) B1f[ks] = f8[(160 + w * 4 + ks) * 64 + l];
#pragma unroll
    for (int ks = 0; ks < 4; ++ks) B2f[ks] = f8[(192 + w * 4 + ks) * 64 + l];
  }
  float bzv[4], wi7[4];
#pragma unroll
  for (int g = 0; g < 4; ++g){
    bzv[g] = bz[g * 128 + w * 16 + c16];
    // Wi[7][col] as the SAME fp16 value the x-MFMA would use (frag elem kk=7)
    wi7[g] = (float)wsb[((w * 4 + g) * 5) * 512 + c16 * 8 + 7];
  }
  const float b1v   = b1[w * 16 + c16];
  const float b2v   = b2[w * 16 + c16];
  const float bout0 = bout[0];
  const float woutv = Wout[w * 16 + c16];   // this lane's head weight

  // per-thread gather bases (threads t<256 own one (row,feature) slot)
  const float* fbase = nullptr;   // feature array base (j<7)
  const float* ibase = nullptr;   // irradiance base (j==7)
  int xslot = 0;
  if (t < 256){
    int r = t >> 3, j = t & 7;
    if (j < 7) fbase = fp.f[j] + (r0 + r) * T_STEPS;
    else       ibase = irr + (r0 + r) * WARM_N;
    xslot = (r >> 4) * 640 + (r & 15) * 40 + j;
  }

  { // zero x buffers (k8..31 pads stay 0 forever) and h buffers (h(-1)=0)
    int* zp = (int*)&xp[0][0];
    for (int i = t; i < 1920; i += 512) zp[i] = 0;
    zp = (int*)&hp[0][0];
    for (int i = t; i < 5120; i += 512) zp[i] = 0;
    if (t < 64) pS[t >> 5][t & 31] = bout0;
  }

  float cst[8];
#pragma unroll
  for (int i = 0; i < 8; ++i) cst[i] = 0.0f;

  const int aoff = c16 * 40 + kq * 8;                    // A-frag read offset
  const int wb   = (w >> 1) * 1280 + (w & 1) * 16 + c16; // h/o1 write base
  __syncthreads();

  // prologue: gather x(0) into xp[0]
  if (t < 256){
    float v0 = fbase ? fbase[0] : ibase[0];
    xp[0][xslot] = (_Float16)v0;
  }
  __syncthreads();

  // ============ warm loop: i = 0..23, ONE barrier per step ============
  // Region i: read xp[i%3], hp[i&1], o1p[i&1], pS[(i+1)&1];
  //           write xp[(i+1)%3], hp[(i+1)&1], o1p[(i+1)&1], pS[i&1] (atomic).
  // All read/write sets disjoint within the region; barrier publishes.
  for (int i = 0; i < 24; ++i){
    // stage x(i+1): steps 1..24 (j7: real irr if step<24, else 0)
    float vnext = 0.0f;
    if (t < 256){
      int step = i + 1;
      if (fbase)               vnext = fbase[step];
      else if (step < WARM_N)  vnext = ibase[step];
    }
    // z(i) + MLP1(i-1) fused on shared h-panel reads
    float4v acc[4][2];
#pragma unroll
    for (int g = 0; g < 4; ++g)
#pragma unroll
      for (int m = 0; m < 2; ++m)
#pragma unroll
        for (int r = 0; r < 4; ++r) acc[g][m][r] = bzv[g];
    float4v m1[2];
#pragma unroll
    for (int m = 0; m < 2; ++m)
#pragma unroll
      for (int r = 0; r < 4; ++r) m1[m][r] = b1v;
    {
      const _Float16* xb = xp[i % 3];
      h8 a0 = *(const h8*)&xb[aoff];
      h8 a1 = *(const h8*)&xb[640 + aoff];
#pragma unroll
      for (int g = 0; g < 4; ++g){
        acc[g][0] = MFMA16(a0, Bz[g][0], acc[g][0], 0, 0, 0);
        acc[g][1] = MFMA16(a1, Bz[g][0], acc[g][1], 0, 0, 0);
      }
    }
    {
      const _Float16* hb = hp[i & 1];
#pragma unroll
      for (int ks = 0; ks < 4; ++ks){
        h8 ah0 = *(const h8*)&hb[ks * 1280 + aoff];
        h8 ah1 = *(const h8*)&hb[ks * 1280 + 640 + aoff];
#pragma unroll
        for (int g = 0; g < 4; ++g){
          acc[g][0] = MFMA16(ah0, Bz[g][1 + ks], acc[g][0], 0, 0, 0);
          acc[g][1] = MFMA16(ah1, Bz[g][1 + ks], acc[g][1], 0, 0, 0);
        }
        if (i >= 1){
          m1[0] = MFMA16(ah0, B1f[ks], m1[0], 0, 0, 0);
          m1[1] = MFMA16(ah1, B1f[ks], m1[1], 0, 0, 0);
        }
      }
    }
    if (i >= 1){ // o1(i-1) -> o1p[(i+1)&1]  ((i-1)&1 == (i+1)&1)
      _Float16* o1w = o1p[(i + 1) & 1];
#pragma unroll
      for (int m = 0; m < 2; ++m)
#pragma unroll
        for (int r = 0; r < 4; ++r)
          o1w[wb + m * 640 + (kq * 4 + r) * 40] = (_Float16)fmaxf(m1[m][r], 0.0f);
    }
    { // gates(i): acc -> c,h; write h(i) -> hp[(i+1)&1]
      _Float16* hw = hp[(i + 1) & 1];
#pragma unroll
      for (int m = 0; m < 2; ++m)
#pragma unroll
        for (int r = 0; r < 4; ++r){
          float zi = acc[0][m][r], zf = acc[1][m][r], zg = acc[2][m][r], zo = acc[3][m][r];
          float c2 = sigm(zf) * cst[m * 4 + r] + sigm(zi) * tanh_(zg);
          cst[m * 4 + r] = c2;
          float h2 = sigm(zo) * tanh_(c2);
          hw[wb + m * 640 + (kq * 4 + r) * 40] = (_Float16)h2;  // row = kq*4+r
        }
    }
    if (i >= 2){ // MLP2(i-2) + head-reduce -> pS[i&1]
      float4v m2[2];
#pragma unroll
      for (int m = 0; m < 2; ++m)
#pragma unroll
        for (int r = 0; r < 4; ++r) m2[m][r] = b2v;
      const _Float16* o1r = o1p[i & 1];
#pragma unroll
      for (int ks = 0; ks < 4; ++ks){
        h8 a0 = *(const h8*)&o1r[ks * 1280 + aoff];
        h8 a1 = *(const h8*)&o1r[ks * 1280 + 640 + aoff];
        m2[0] = MFMA16(a0, B2f[ks], m2[0], 0, 0, 0);
        m2[1] = MFMA16(a1, B2f[ks], m2[1], 0, 0, 0);
      }
#pragma unroll
      for (int m = 0; m < 2; ++m)
#pragma unroll
        for (int r = 0; r < 4; ++r){
          float v = fmaxf(m2[m][r], 0.0f) * woutv;
          v += __shfl_xor(v, 1);
          v += __shfl_xor(v, 2);
          v += __shfl_xor(v, 4);
          v += __shfl_xor(v, 8);
          if (c16 == 0) atomicAdd(&pS[i & 1][m * 16 + kq * 4 + r], v);
        }
    }
    if (i >= 3 && t < 32){ // out(i-3) from pS[(i+1)&1] (=p(i-3)), then reset
      float pv = pS[(i + 1) & 1][t];
      out[(r0 + t) * T_STEPS + (i - 3)] = pv;
      pS[(i + 1) & 1][t] = bout0;
    }
    if (t < 256) xp[(i + 1) % 3][xslot] = (_Float16)vnext;
    __syncthreads();
  }
  // After warm: h(23) in hp[0]; o1(22) in o1p[0]; p(21) in pS[1];
  // out written through step 20. Pending: out(21), MLP2(22)->out(22).

  // ===== tail: s = 24..29, 3 barriers/step (p-feedback chain) =====
  for (int s = 24; s < T_STEPS; ++s){
    // ---- TA: z(s) (j7=0 in xp) + MLP1(s-1); stage x(s+1); pSt=bout0 ----
    float vnext = 0.0f;
    if (s <= 28 && t < 256 && fbase) vnext = fbase[s + 1];  // j7 stays 0
    float4v acc[4][2];
#pragma unroll
    for (int g = 0; g < 4; ++g)
#pragma unroll
      for (int m = 0; m < 2; ++m)
#pragma unroll
        for (int r = 0; r < 4; ++r) acc[g][m][r] = bzv[g];
    float4v m1[2];
#pragma unroll
    for (int m = 0; m < 2; ++m)
#pragma unroll
      for (int r = 0; r < 4; ++r) m1[m][r] = b1v;
    {
      const _Float16* xb = xp[s % 3];
      h8 a0 = *(const h8*)&xb[aoff];
      h8 a1 = *(const h8*)&xb[640 + aoff];
#pragma unroll
      for (int g = 0; g < 4; ++g){
        acc[g][0] = MFMA16(a0, Bz[g][0], acc[g][0], 0, 0, 0);
        acc[g][1] = MFMA16(a1, Bz[g][0], acc[g][1], 0, 0, 0);
      }
    }
    {
      const _Float16* hb = hp[s & 1];
#pragma unroll
      for (int ks = 0; ks < 4; ++ks){
        h8 ah0 = *(const h8*)&hb[ks * 1280 + aoff];
        h8 ah1 = *(const h8*)&hb[ks * 1280 + 640 + aoff];
#pragma unroll
        for (int g = 0; g < 4; ++g){
          acc[g][0] = MFMA16(ah0, Bz[g][1 + ks], acc[g][0], 0, 0, 0);
          acc[g][1] = MFMA16(ah1, Bz[g][1 + ks], acc[g][1], 0, 0, 0);
        }
        m1[0] = MFMA16(ah0, B1f[ks], m1[0], 0, 0, 0);
        m1[1] = MFMA16(ah1, B1f[ks], m1[1], 0, 0, 0);
      }
    }
    { // o1(s-1) -> o1p[(s+1)&1]
      _Float16* o1w = o1p[(s + 1) & 1];
#pragma unroll
      for (int m = 0; m < 2; ++m)
#pragma unroll
        for (int r = 0; r < 4; ++r)
          o1w[wb + m * 640 + (kq * 4 + r) * 40] = (_Float16)fmaxf(m1[m][r], 0.0f);
    }
    if (s == 24){ // leftover warm work: out(21); MLP2(22)+reduce -> pS[0]
      if (t < 32) out[(r0 + t) * T_STEPS + 21] = pS[1][t];
      float4v m2[2];
#pragma unroll
      for (int m = 0; m < 2; ++m)
#pragma unroll
        for (int r = 0; r < 4; ++r) m2[m][r] = b2v;
      const _Float16* o1r = o1p[0];
#pragma unroll
      for (int ks = 0; ks < 4; ++ks){
        h8 a0 = *(const h8*)&o1r[ks * 1280 + aoff];
        h8 a1 = *(const h8*)&o1r[ks * 1280 + 640 + aoff];
        m2[0] = MFMA16(a0, B2f[ks], m2[0], 0, 0, 0);
        m2[1] = MFMA16(a1, B2f[ks], m2[1], 0, 0, 0);
      }
#pragma unroll
      for (int m = 0; m < 2; ++m)
#pragma unroll
        for (int r = 0; r < 4; ++r){
          float v = fmaxf(m2[m][r], 0.0f) * woutv;
          v += __shfl_xor(v, 1);
          v += __shfl_xor(v, 2);
          v += __shfl_xor(v, 4);
          v += __shfl_xor(v, 8);
          if (c16 == 0) atomicAdd(&pS[0][m * 16 + kq * 4 + r], v);
        }
    }
    if (t < 32) pSt[t] = bout0;
    if (s <= 28 && t < 256) xp[(s + 1) % 3][xslot] = (_Float16)vnext;
    __syncthreads();

    // ---- TB: MLP2(s-1) + reduce -> pSt (= p(s-1)) ----
    {
      float4v m2[2];
#pragma unroll
      for (int m = 0; m < 2; ++m)
#pragma unroll
        for (int r = 0; r < 4; ++r) m2[m][r] = b2v;
      const _Float16* o1r = o1p[(s + 1) & 1];
#pragma unroll
      for (int ks = 0; ks < 4; ++ks){
        h8 a0 = *(const h8*)&o1r[ks * 1280 + aoff];
        h8 a1 = *(const h8*)&o1r[ks * 1280 + 640 + aoff];
        m2[0] = MFMA16(a0, B2f[ks], m2[0], 0, 0, 0);
        m2[1] = MFMA16(a1, B2f[ks], m2[1], 0, 0, 0);
      }
#pragma unroll
      for (int m = 0; m < 2; ++m)
#pragma unroll
        for (int r = 0; r < 4; ++r){
          float v = fmaxf(m2[m][r], 0.0f) * woutv;
          v += __shfl_xor(v, 1);
          v += __shfl_xor(v, 2);
          v += __shfl_xor(v, 4);
          v += __shfl_xor(v, 8);
          if (c16 == 0) atomicAdd(&pSt[m * 16 + kq * 4 + r], v);
        }
    }
    if (s == 24 && t < 32) out[(r0 + t) * T_STEPS + 22] = pS[0][t];
    __syncthreads();

    // ---- TC: p-inject + gates(s) -> hp[(s+1)&1]; out(s-1) ----
#pragma unroll
    for (int m = 0; m < 2; ++m)
#pragma unroll
      for (int r = 0; r < 4; ++r){
        float pv = pSt[m * 16 + kq * 4 + r];
#pragma unroll
        for (int g = 0; g < 4; ++g) acc[g][m][r] += pv * wi7[g];
      }
    {
      _Float16* hw = hp[(s + 1) & 1];
#pragma unroll
      for (int m = 0; m < 2; ++m)
#pragma unroll
        for (int r = 0; r < 4; ++r){
          float zi = acc[0][m][r], zf = acc[1][m][r], zg = acc[2][m][r], zo = acc[3][m][r];
          float c2 = sigm(zf) * cst[m * 4 + r] + sigm(zi) * tanh_(zg);
          cst[m * 4 + r] = c2;
          float h2 = sigm(zo) * tanh_(c2);
          hw[wb + m * 640 + (kq * 4 + r) * 40] = (_Float16)h2;
        }
    }
    if (t < 32) out[(r0 + t) * T_STEPS + (s - 1)] = pSt[t];
    __syncthreads();
  }

  // ===== final drain: MLP1(29) | MLP2(29)+reduce | out(29) =====
  {
    float4v m1[2];
#pragma unroll
    for (int m = 0; m < 2; ++m)
#pragma unroll
      for (int r = 0; r < 4; ++r) m1[m][r] = b1v;
    const _Float16* hb = hp[0];          // h(29) written in TC(29)
#pragma unroll
    for (int ks = 0; ks < 4; ++ks){
      h8 ah0 = *(const h8*)&hb[ks * 1280 + aoff];
      h8 ah1 = *(const h8*)&hb[ks * 1280 + 640 + aoff];
      m1[0] = MFMA16(ah0, B1f[ks], m1[0], 0, 0, 0);
      m1[1] = MFMA16(ah1, B1f[ks], m1[1], 0, 0, 0);
    }
    _Float16* o1w = o1p[0];
#pragma unroll
    for (int m = 0; m < 2; ++m)
#pragma unroll
      for (int r = 0; r < 4; ++r)
        o1w[wb + m * 640 + (kq * 4 + r) * 40] = (_Float16)fmaxf(m1[m][r], 0.0f);
    if (t < 32) pSt[t] = bout0;
    __syncthreads();

    float4v m2[2];
#pragma unroll
    for (int m = 0; m < 2; ++m)
#pragma unroll
      for (int r = 0; r < 4; ++r) m2[m][r] = b2v;
    const _Float16* o1r = o1p[0];
#pragma unroll
    for (int ks = 0; ks < 4; ++ks){
      h8 a0 = *(const h8*)&o1r[ks * 1280 + aoff];
      h8 a1 = *(const h8*)&o1r[ks * 1280 + 640 + aoff];
      m2[0] = MFMA16(a0, B2f[ks], m2[0], 0, 0, 0);
      m2[1] = MFMA16(a1, B2f[ks], m2[1], 0, 0, 0);
    }
#pragma unroll
    for (int m = 0; m < 2; ++m)
#pragma unroll
      for (int r = 0; r < 4; ++r){
        float v = fmaxf(m2[m][r], 0.0f) * woutv;
        v += __shfl_xor(v, 1);
        v += __shfl_xor(v, 2);
        v += __shfl_xor(v, 4);
        v += __shfl_xor(v, 8);
        if (c16 == 0) atomicAdd(&pSt[m * 16 + kq * 4 + r], v);
      }
    __syncthreads();

    if (t < 32) out[(r0 + t) * T_STEPS + 29] = pSt[t];
  }
}

extern "C" void kernel_launch(void* const* d_in, const int* in_sizes, int n_in,
                              void* d_out, int out_size, void* d_ws, size_t ws_size,
                              hipStream_t stream)
{
  (void)in_sizes; (void)n_in; (void)out_size; (void)ws_size;
  // inputs: 0..7 weather (unused), 8..14 time feats, 15 irradiance_in,
  // 16 Wi, 17 Wh, 18 b, 19 W1, 20 b1, 21 W2, 22 b2, 23 Wout, 24 bout
  FeatPtrs fp;
  for (int j = 0; j < 7; ++j) fp.f[j] = (const float*)d_in[8 + j];
  const float* irr  = (const float*)d_in[15];
  const float* Wi   = (const float*)d_in[16];
  const float* Wh   = (const float*)d_in[17];
  const float* bz   = (const float*)d_in[18];
  const float* W1   = (const float*)d_in[19];
  const float* b1   = (const float*)d_in[20];
  const float* W2   = (const float*)d_in[21];
  const float* b2   = (const float*)d_in[22];
  const float* Wout = (const float*)d_in[23];
  const float* bout = (const float*)d_in[24];

  _Float16* ws = (_Float16*)d_ws;                 // 224*512*2 = 224 KB used
  pack_weights<<<dim3(448), dim3(256), 0, stream>>>(Wi, Wh, W1, W2, ws);
  lstm_mfma<<<dim3(256), dim3(512), 0, stream>>>(
      fp, irr, ws, bz, b1, b2, Wout, bout, (float*)d_out);
}

// Round 11
// 177.851 us; speedup vs baseline: 1.1981x; 1.1981x over previous
//
#include <hip/hip_runtime.h>

// Fused LSTM(H=128) + 3-layer MLP head, fp16 MFMA (16x16x32), fp32 state.
// B=8192 rows, T=30 steps. 256 blocks x 512 threads (8 waves), 32 rows/block.
// ROUND 11: STAGGERED M-TILES on the r7 base (90.5us best). r7's warm runs all
// waves in lockstep {MFMA phase | barrier | VALU phase | barrier} -> each pipe
// idles half the time (MfmaUtil 25 / VALUBusy 49). r10's mega-region fix
// REGRESSED (121us: shuffle-head added ~32 LDS-pipe ops/thread + reg pressure).
// This round: same r7 primitives, but the two independent 16-row M-tiles are
// phase-shifted inside each wave:
//   region A_i: m0: z(i)+MLP1(i-1) [MFMA]  | m1: gates(i-1)+MLP2(i-2)+head [VALU]
//   region B_i: m1: z(i)+MLP1(i-1) [MFMA]  | m0: gates(i)+MLP2(i-1)+head  [VALU]
// -> every region co-issues ~28 MFMAs with ~40 trans ops from the same wave.
// Same barriers/step (2), same head table (o2s + 16FMA reduce), same LDS, same
// register totals (one tile's acc crosses each barrier; 32 total as r7).
// Accumulation order per accumulator identical -> absmax bit-identical.
// Buffers: xp dbuf (x steps), hp/o1p/o2s single (row-halves alternate:
// A writes rows16-31 of hp/o2s + rows0-15 of o1p; B the complements; every
// producer->consumer pair crosses >=1 barrier - audited per-buffer below).
// i=0,1 peeled so the 22 hot warm iterations are branchless.
// Tail: drain {gates(23)m1 + MLP2(22)m1 + head0(22)} | {head1(22)}, then r7's
// proven TA/TB/TC/TD tail for s=24..29 (p-inject via acc += p*wi7) + drain(29).
// Prior lessons: 2 waves/SIMD is the reg ceiling (r4/r5 spills; watch FETCH);
// fp16 single precision (r7); no shuffle-head (r10); no async gather split (r8).

#define T_STEPS 30
#define WARM_N  24

typedef _Float16 h8 __attribute__((ext_vector_type(8)));     // 8 fp16 = 4 VGPRs
typedef __attribute__((ext_vector_type(4))) float float4v;   // MFMA 16x16 C/D

struct FeatPtrs { const float* f[7]; };

#if __has_builtin(__builtin_amdgcn_rcpf)
#define RCP(x) __builtin_amdgcn_rcpf(x)
#else
#define RCP(x) (1.0f/(x))
#endif

__device__ __forceinline__ float sigm(float x){ return RCP(1.0f + __expf(-x)); }
__device__ __forceinline__ float tanh_(float x){ return 1.0f - 2.0f*RCP(1.0f + __expf(2.0f*x)); }

// ---------------- weight pack kernel (identical to r7) ----------------
// 224 frags of 512 fp16 (1 KB each), frag elem (lane,j):
//   col16 = lane&15, kk = (lane>>4)*8 + j  (K=32 per fragment)
// frags 0..159 : z-weights [wt 0..7][g 0..3][ks 0..4]
//   ks=0: x-frag: kk<8 -> Wi[kk][col], kk>=8 -> 0
//   ks 1..4: Wh[(ks-1)*32+kk][col];  col = g*128+wt*16+col16
// frags 160..191: W1 [wt][ks 0..3]; 192..223: W2 same layout.
__global__ void pack_weights(const float* __restrict__ Wi, const float* __restrict__ Wh,
                             const float* __restrict__ W1, const float* __restrict__ W2,
                             _Float16* __restrict__ ws)
{
  int idx = blockIdx.x * 256 + threadIdx.x;
  if (idx >= 224 * 512) return;
  int f    = idx >> 9;
  int r    = idx & 511;
  int lane = r >> 3, j = r & 7;
  int kk   = ((lane >> 4) << 3) + j;     // 0..31
  int c16  = lane & 15;
  float v = 0.0f;
  if (f < 160){
    int wt = f / 20, rem = f % 20, g = rem / 5, ks = rem % 5;
    int col = g * 128 + wt * 16 + c16;
    if (ks == 0) v = (kk < 8) ? Wi[kk * 512 + col] : 0.0f;
    else         v = Wh[((ks - 1) * 32 + kk) * 512 + col];
  } else {
    int f2 = f - 160;
    const float* W = (f2 < 32) ? W1 : W2;
    int f3 = f2 & 31;
    int wt = f3 >> 2, ks = f3 & 3;
    v = W[(ks * 32 + kk) * 128 + wt * 16 + c16];
  }
  ws[idx] = (_Float16)v;
}

#define MFMA16 __builtin_amdgcn_mfma_f32_16x16x32_f16

// ---------------- region building blocks ----------------
#define INIT_ACC(ACC) \
  _Pragma("unroll") for (int g_ = 0; g_ < 4; ++g_) \
    _Pragma("unroll") for (int r_ = 0; r_ < 4; ++r_) ACC[g_][r_] = bzv[g_];

#define INIT4(V, B) \
  _Pragma("unroll") for (int r_ = 0; r_ < 4; ++r_) V[r_] = (B);

// z-GEMM for one m-tile (+ optionally MLP1 fused on the same h reads)
#define ZA(ACC, M1V, XBUF, HOFF, DO1) \
  { h8 ax_ = *(const h8*)&xp[XBUF][(HOFF) + aoff]; \
    _Pragma("unroll") for (int g_ = 0; g_ < 4; ++g_) \
      ACC[g_] = MFMA16(ax_, Bz[g_][0], ACC[g_], 0, 0, 0); } \
  _Pragma("unroll") for (int ks_ = 0; ks_ < 4; ++ks_){ \
    h8 ah_ = *(const h8*)&hp[ks_ * 1280 + (HOFF) + aoff]; \
    _Pragma("unroll") for (int g_ = 0; g_ < 4; ++g_) \
      ACC[g_] = MFMA16(ah_, Bz[g_][1 + ks_], ACC[g_], 0, 0, 0); \
    if (DO1) M1V = MFMA16(ah_, B1f[ks_], M1V, 0, 0, 0); }

#define WRITE_O1(M1V, HOFF) \
  _Pragma("unroll") for (int r_ = 0; r_ < 4; ++r_) \
    o1p[wb + (HOFF) + (kq * 4 + r_) * 40] = (_Float16)fmaxf(M1V[r_], 0.0f);

#define GATES(ACC, CB, HOFF) \
  _Pragma("unroll") for (int r_ = 0; r_ < 4; ++r_){ \
    float zi_ = ACC[0][r_], zf_ = ACC[1][r_], zg_ = ACC[2][r_], zo_ = ACC[3][r_]; \
    float c2_ = sigm(zf_) * cst[(CB) + r_] + sigm(zi_) * tanh_(zg_); \
    cst[(CB) + r_] = c2_; \
    float h2_ = sigm(zo_) * tanh_(c2_); \
    hp[wb + (HOFF) + (kq * 4 + r_) * 40] = (_Float16)h2_; }

#define DO_MLP2(HOFF, ROWB) \
  { float4v m2_; INIT4(m2_, b2v) \
    _Pragma("unroll") for (int ks_ = 0; ks_ < 4; ++ks_){ \
      h8 a_ = *(const h8*)&o1p[ks_ * 1280 + (HOFF) + aoff]; \
      m2_ = MFMA16(a_, B2f[ks_], m2_, 0, 0, 0); } \
    _Pragma("unroll") for (int r_ = 0; r_ < 4; ++r_) \
      o2s[((ROWB) + kq * 4 + r_) * 132 + w * 16 + c16] = fmaxf(m2_[r_], 0.0f); }

// head for one 16-row half: 8 threads/row, 16-col strips, fp32 exact
#define HEAD_HALF(TLO, RB, STEP) \
  if (t >= (TLO) && t < (TLO) + 128){ \
    int r_ = (RB) + ((t - (TLO)) >> 3), jj_ = t & 7; \
    const float* orow_ = &o2s[r_ * 132 + jj_ * 16]; \
    const float* wrow_ = &WoutS[jj_ * 16]; \
    float s_ = 0.0f; \
    _Pragma("unroll") for (int q_ = 0; q_ < 16; ++q_) s_ += orow_[q_] * wrow_[q_]; \
    s_ += __shfl_down(s_, 4, 8); s_ += __shfl_down(s_, 2, 8); s_ += __shfl_down(s_, 1, 8); \
    if (jj_ == 0){ float pv_ = s_ + bout0; \
      out[(r0 + r_) * T_STEPS + (STEP)] = pv_; pS[r_] = pv_; } }

#define STAGE_WARM(STEP, BUF) \
  if (t < 256){ \
    float v_ = 0.0f; \
    if (fbase) v_ = fbase[STEP]; \
    else if ((STEP) < WARM_N) v_ = ibase[STEP]; \
    xp[BUF][xslot] = (_Float16)v_; }

#define STAGE_TAIL(STEP, BUF) \
  if (t < 256){ \
    float v_ = fbase ? fbase[STEP] : 0.0f; \
    xp[BUF][xslot] = (_Float16)v_; }

// ---------------- main kernel ----------------
__global__ __launch_bounds__(512, 2)
void lstm_mfma(FeatPtrs fp, const float* __restrict__ irr,
               const _Float16* __restrict__ wsb,
               const float* __restrict__ bz, const float* __restrict__ b1,
               const float* __restrict__ b2, const float* __restrict__ Wout,
               const float* __restrict__ bout, float* __restrict__ out)
{
  // A-panels: [m-tile][16 rows][40 halfs] (32 data + 8 pad), b128-aligned
  __shared__ __align__(16) _Float16 xp[2][1280];    // x, double-buffered steps
  __shared__ __align__(16) _Float16 hp [4 * 1280];  // h, single (halves alternate)
  __shared__ __align__(16) _Float16 o1p[4 * 1280];  // o1, single
  __shared__ __align__(16) float o2s[32 * 132];     // o2 fp32, padded rows
  __shared__ float WoutS[128];
  __shared__ float pS[32];

  const int t   = threadIdx.x;
  const int l   = t & 63;
  const int w   = t >> 6;        // wave 0..7, owns cols [16w,16w+16)
  const int c16 = l & 15;
  const int kq  = l >> 4;        // 0..3
  const int r0  = blockIdx.x * 32;

  // weight fragments -> registers (112 VGPRs)
  h8 Bz[4][5], B1f[4], B2f[4];
  {
    const h8* f8 = (const h8*)wsb;
#pragma unroll
    for (int g = 0; g < 4; ++g)
#pragma unroll
      for (int ks = 0; ks < 5; ++ks)
        Bz[g][ks] = f8[((w * 4 + g) * 5 + ks) * 64 + l];
#pragma unroll
    for (int ks = 0; ks < 4; ++ks) B1f[ks] = f8[(160 + w * 4 + ks) * 64 + l];
#pragma unroll
    for (int ks = 0; ks < 4; ++ks) B2f[ks] = f8[(192 + w * 4 + ks) * 64 + l];
  }
  float bzv[4], wi7[4];
#pragma unroll
  for (int g = 0; g < 4; ++g){
    bzv[g] = bz[g * 128 + w * 16 + c16];
    // Wi[7][col] as the SAME fp16 value the x-MFMA would use (frag elem kk=7)
    wi7[g] = (float)wsb[((w * 4 + g) * 5) * 512 + c16 * 8 + 7];
  }
  const float b1v   = b1[w * 16 + c16];
  const float b2v   = b2[w * 16 + c16];
  const float bout0 = bout[0];
  if (t < 128) WoutS[t] = Wout[t];

  // per-thread gather bases (threads t<256 own one (row,feature) slot)
  const float* fbase = nullptr;   // feature array base (j<7)
  const float* ibase = nullptr;   // irradiance base (j==7)
  int xslot = 0;
  if (t < 256){
    int r = t >> 3, j = t & 7;
    if (j < 7) fbase = fp.f[j] + (r0 + r) * T_STEPS;
    else       ibase = irr + (r0 + r) * WARM_N;
    xslot = (r >> 4) * 640 + (r & 15) * 40 + j;
  }

  { // zero x buffers (k8..31 pads stay 0 forever) and h panels (h(-1)=0)
    int* zp = (int*)&xp[0][0];
    for (int i = t; i < 1280; i += 512) zp[i] = 0;
    zp = (int*)hp;
    for (int i = t; i < 2560; i += 512) zp[i] = 0;
  }

  float cst[8];   // [0..3]=m0 rows0-15, [4..7]=m1 rows16-31
#pragma unroll
  for (int i = 0; i < 8; ++i) cst[i] = 0.0f;

  const int aoff = c16 * 40 + kq * 8;                    // A-frag read offset
  const int wb   = (w >> 1) * 1280 + (w & 1) * 16 + c16; // h/o1 write base
  __syncthreads();

  // prologue: gather x(0) into xp[0]
  if (t < 256){
    float v0 = fbase ? fbase[0] : ibase[0];
    xp[0][xslot] = (_Float16)v0;
  }
  __syncthreads();

  float4v acc0[4], acc1[4];  // m0 acc (A->B), m1 acc (B->next A)
  float4v m1a, m1b;

  // ================= peeled i=0 =================
  STAGE_WARM(1, 1)                    // x(1) -> xp[1]
  INIT_ACC(acc0)
  ZA(acc0, m1a, 0, 0, 0)              // m0 z(0); h(-1)=0
  __syncthreads();

  INIT_ACC(acc1)
  ZA(acc1, m1b, 0, 640, 0)            // m1 z(0)
  GATES(acc0, 0, 0)                   // m0 gates(0) -> hp rows0-15
  __syncthreads();

  // ================= peeled i=1 =================
  STAGE_WARM(2, 0)                    // x(2) -> xp[0]
  INIT_ACC(acc0)
  INIT4(m1a, b1v)
  ZA(acc0, m1a, 1, 0, 1)              // m0 z(1)+MLP1(0)
  WRITE_O1(m1a, 0)                    // o1(0) rows0-15
  GATES(acc1, 4, 640)                 // m1 gates(0) -> hp rows16-31
  __syncthreads();

  INIT_ACC(acc1)
  INIT4(m1b, b1v)
  ZA(acc1, m1b, 1, 640, 1)            // m1 z(1)+MLP1(0)
  WRITE_O1(m1b, 640)                  // o1(0) rows16-31
  GATES(acc0, 0, 0)                   // m0 gates(1)
  DO_MLP2(0, 0)                       // m0 MLP2(0) -> o2s rows0-15
  __syncthreads();

  // ================= warm main: i = 2..23 (branchless regions) ============
  for (int i = 2; i < 24; ++i){
    const int xbi = i & 1, xbo = (i + 1) & 1;
    // ---- region A: m0 MFMA | m1 VALU ----
    STAGE_WARM(i + 1, xbo)            // x(i+1); step 24 -> j7 stays 0
    INIT_ACC(acc0)
    INIT4(m1a, b1v)
    ZA(acc0, m1a, xbi, 0, 1)          // m0 z(i)+MLP1(i-1)
    WRITE_O1(m1a, 0)                  // o1(i-1) rows0-15
    GATES(acc1, 4, 640)               // m1 gates(i-1) -> hp rows16-31
    DO_MLP2(640, 16)                  // m1 MLP2(i-2) -> o2s rows16-31
    HEAD_HALF(0, 0, i - 2)            // out(i-2) rows0-15 (o2 from B_{i-1})
    __syncthreads();

    // ---- region B: m1 MFMA | m0 VALU ----
    INIT_ACC(acc1)
    INIT4(m1b, b1v)
    ZA(acc1, m1b, xbi, 640, 1)        // m1 z(i)+MLP1(i-1) (h1(i-1) from A_i)
    WRITE_O1(m1b, 640)                // o1(i-1) rows16-31
    GATES(acc0, 0, 0)                 // m0 gates(i) -> hp rows0-15
    DO_MLP2(0, 0)                     // m0 MLP2(i-1) -> o2s rows0-15
    HEAD_HALF(128, 16, i - 2)         // out(i-2) rows16-31 (o2 from A_i)
    __syncthreads();
  }
  // After warm: h0(23) in hp (B_23), acc1 = z(23) m1; o1(22) both halves done;
  // o2(22) rows0-15 from B_23; out complete through step 21.

  // ================= drain to synchronized state =================
  GATES(acc1, 4, 640)                 // m1 gates(23) -> h1(23)
  DO_MLP2(640, 16)                    // m1 MLP2(22) -> o2s rows16-31
  HEAD_HALF(0, 0, 22)                 // out(22) rows0-15 (o2 from B_23)
  __syncthreads();
  HEAD_HALF(128, 16, 22)              // out(22) rows16-31 (o2 from drain R1)
  __syncthreads();

  // ===== tail: s = 24..29 (r7's proven TA/TB/TC/TD; p-feedback chain) =====
  for (int s = 24; s < T_STEPS; ++s){
    // ---- TA: stage x(s+1) (j7=0) | z(s)+MLP1(s-1) both m -> o1p ----
    if (s <= 28){ STAGE_TAIL(s + 1, (s + 1) & 1) }
    float4v acc[4][2];
#pragma unroll
    for (int g = 0; g < 4; ++g)
#pragma unroll
      for (int m = 0; m < 2; ++m)
#pragma unroll
        for (int r = 0; r < 4; ++r) acc[g][m][r] = bzv[g];
    float4v m1[2];
#pragma unroll
    for (int m = 0; m < 2; ++m)
#pragma unroll
      for (int r = 0; r < 4; ++r) m1[m][r] = b1v;
    {
      const _Float16* xb = xp[s & 1];
      h8 a0 = *(const h8*)&xb[aoff];
      h8 a1 = *(const h8*)&xb[640 + aoff];
#pragma unroll
      for (int g = 0; g < 4; ++g){
        acc[g][0] = MFMA16(a0, Bz[g][0], acc[g][0], 0, 0, 0);
        acc[g][1] = MFMA16(a1, Bz[g][0], acc[g][1], 0, 0, 0);
      }
    }
#pragma unroll
    for (int ks = 0; ks < 4; ++ks){
      h8 ah0 = *(const h8*)&hp[ks * 1280 + aoff];
      h8 ah1 = *(const h8*)&hp[ks * 1280 + 640 + aoff];
#pragma unroll
      for (int g = 0; g < 4; ++g){
        acc[g][0] = MFMA16(ah0, Bz[g][1 + ks], acc[g][0], 0, 0, 0);
        acc[g][1] = MFMA16(ah1, Bz[g][1 + ks], acc[g][1], 0, 0, 0);
      }
      m1[0] = MFMA16(ah0, B1f[ks], m1[0], 0, 0, 0);
      m1[1] = MFMA16(ah1, B1f[ks], m1[1], 0, 0, 0);
    }
#pragma unroll
    for (int m = 0; m < 2; ++m)
#pragma unroll
      for (int r = 0; r < 4; ++r)
        o1p[wb + m * 640 + (kq * 4 + r) * 40] = (_Float16)fmaxf(m1[m][r], 0.0f);
    __syncthreads();

    // ---- TB: MLP2(s-1) both m -> o2s ----
    DO_MLP2(0, 0)
    DO_MLP2(640, 16)
    __syncthreads();

    // ---- TC: head(s-1) full -> out, pS ----
    HEAD_HALF(0, 0, s - 1)
    HEAD_HALF(128, 16, s - 1)
    __syncthreads();

    // ---- TD: p-inject + gates(s) both m -> hp ----
#pragma unroll
    for (int m = 0; m < 2; ++m)
#pragma unroll
      for (int r = 0; r < 4; ++r){
        float pv = pS[m * 16 + kq * 4 + r];
#pragma unroll
        for (int g = 0; g < 4; ++g) acc[g][m][r] += pv * wi7[g];
      }
#pragma unroll
    for (int m = 0; m < 2; ++m)
#pragma unroll
      for (int r = 0; r < 4; ++r){
        float zi = acc[0][m][r], zf = acc[1][m][r], zg = acc[2][m][r], zo = acc[3][m][r];
        float c2 = sigm(zf) * cst[m * 4 + r] + sigm(zi) * tanh_(zg);
        cst[m * 4 + r] = c2;
        float h2 = sigm(zo) * tanh_(c2);
        hp[wb + m * 640 + (kq * 4 + r) * 40] = (_Float16)h2;
      }
    __syncthreads();
  }

  // ===== final drain: MLP1(29) | MLP2(29) | head(29) =====
  {
    float4v m1[2];
#pragma unroll
    for (int m = 0; m < 2; ++m)
#pragma unroll
      for (int r = 0; r < 4; ++r) m1[m][r] = b1v;
#pragma unroll
    for (int ks = 0; ks < 4; ++ks){
      h8 ah0 = *(const h8*)&hp[ks * 1280 + aoff];
      h8 ah1 = *(const h8*)&hp[ks * 1280 + 640 + aoff];
      m1[0] = MFMA16(ah0, B1f[ks], m1[0], 0, 0, 0);
      m1[1] = MFMA16(ah1, B1f[ks], m1[1], 0, 0, 0);
    }
#pragma unroll
    for (int m = 0; m < 2; ++m)
#pragma unroll
      for (int r = 0; r < 4; ++r)
        o1p[wb + m * 640 + (kq * 4 + r) * 40] = (_Float16)fmaxf(m1[m][r], 0.0f);
    __syncthreads();
    DO_MLP2(0, 0)
    DO_MLP2(640, 16)
    __syncthreads();
    HEAD_HALF(0, 0, 29)
    HEAD_HALF(128, 16, 29)
  }
}

extern "C" void kernel_launch(void* const* d_in, const int* in_sizes, int n_in,
                              void* d_out, int out_size, void* d_ws, size_t ws_size,
                              hipStream_t stream)
{
  (void)in_sizes; (void)n_in; (void)out_size; (void)ws_size;
  // inputs: 0..7 weather (unused), 8..14 time feats, 15 irradiance_in,
  // 16 Wi, 17 Wh, 18 b, 19 W1, 20 b1, 21 W2, 22 b2, 23 Wout, 24 bout
  FeatPtrs fp;
  for (int j = 0; j < 7; ++j) fp.f[j] = (const float*)d_in[8 + j];
  const float* irr  = (const float*)d_in[15];
  const float* Wi   = (const float*)d_in[16];
  const float* Wh   = (const float*)d_in[17];
  const float* bz   = (const float*)d_in[18];
  const float* W1   = (const float*)d_in[19];
  const float* b1   = (const float*)d_in[20];
  const float* W2   = (const float*)d_in[21];
  const float* b2   = (const float*)d_in[22];
  const float* Wout = (const float*)d_in[23];
  const float* bout = (const float*)d_in[24];

  _Float16* ws = (_Float16*)d_ws;                 // 224*512*2 = 224 KB used
  pack_weights<<<dim3(448), dim3(256), 0, stream>>>(Wi, Wh, W1, W2, ws);
  lstm_mfma<<<dim3(256), dim3(512), 0, stream>>>(
      fp, irr, ws, bz, b1, b2, Wout, bout, (float*)d_out);
}